// Round 15
// baseline (174.722 us; speedup 1.0000x reference)
//
#include <hip/hip_runtime.h>

#define NPTS 2048
#define KNBR 16

typedef __attribute__((ext_vector_type(8))) short bf16x8;
typedef __attribute__((ext_vector_type(4))) float f32x4;
union U8 { bf16x8 v; unsigned u[4]; };
union F4 { f32x4 v; float4 q; };

// gfx950 packed f32->bf16 (RNE)
static __device__ __forceinline__ unsigned pk2(float lo, float hi) {
    unsigned r;
    asm("v_cvt_pk_bf16_f32 %0, %1, %2" : "=v"(r) : "v"(lo), "v"(hi));
    return r;
}

// tanh-approx gelu, sigmoid form via exp2 (R11-R13-proven)
static __device__ __forceinline__ float gelu(float x) {
    float x2 = x * x;
    float u  = x * fmaf(x2, 0.044715f, 1.0f);
    float e  = __builtin_amdgcn_exp2f(u * -2.3022083f);
    return x * __builtin_amdgcn_rcpf(1.0f + e);
}

// ---------------------------------------------------------------------------
// phase 1: G[node][c1] = (h[node] . W1 rows 128..255)[c1], bf16, to d_ws.
// Transposed MFMA (R12-proven): lane(q,lm) reg r = G[c1=16nt+4q+r][node lm&3].
__global__ __launch_bounds__(1024) void edge_phase1(
    const float* __restrict__ h, const float* __restrict__ W1,
    short* __restrict__ G)
{
    __shared__ short w1bfs[16384];
    const int tid = threadIdx.x, lane = tid & 63, wave = tid >> 6;
    const int quad = lane >> 4, lm = lane & 15;

    for (int c = tid; c < 2048; c += 1024) {
        const int l = c & 63, fi = c >> 6;
        const int lrow = (l >> 4) * 8, lcol = l & 15;
        const int ks = fi & 3, nt = fi >> 2;
        const int row0 = 128 + ks * 32 + lrow, col = nt * 16 + lcol;
        U8 t;
        #pragma unroll
        for (int p = 0; p < 4; ++p)
            t.u[p] = pk2(W1[(row0 + 2*p) * 128 + col],
                         W1[(row0 + 2*p + 1) * 128 + col]);
        ((bf16x8*)w1bfs)[c] = t.v;
    }
    __syncthreads();
    const bf16x8* w1bf = (const bf16x8*)w1bfs;

    const int sb = (blockIdx.x & 7) * 32 + (blockIdx.x >> 3);
    const int node0 = sb * 64 + wave * 4;
    const int bidx = node0 >> 11, nloc = node0 & 2047;
    const float4* hb4 = (const float4*)h + (size_t)bidx * NPTS * 32;
    short* Gb = G + (size_t)bidx * NPTS * 128;

    const float4* hsrc = hb4 + (size_t)(nloc + (lm & 3)) * 32;
    bf16x8 af[4];
    #pragma unroll
    for (int ks = 0; ks < 4; ++ks) {
        float4 p0 = hsrc[ks * 8 + quad * 2];
        float4 p1 = hsrc[ks * 8 + quad * 2 + 1];
        U8 t;
        t.u[0] = pk2(p0.x, p0.y); t.u[1] = pk2(p0.z, p0.w);
        t.u[2] = pk2(p1.x, p1.y); t.u[3] = pk2(p1.z, p1.w);
        af[ks] = t.v;
    }
    f32x4 gacc[8];
    #pragma unroll
    for (int nt = 0; nt < 8; ++nt) gacc[nt] = (f32x4){0.f, 0.f, 0.f, 0.f};
    #pragma unroll
    for (int ks = 0; ks < 4; ++ks)
        #pragma unroll
        for (int nt = 0; nt < 8; ++nt)
            gacc[nt] = __builtin_amdgcn_mfma_f32_16x16x32_bf16(
                w1bf[(nt * 4 + ks) * 64 + lane], af[ks], gacc[nt], 0, 0, 0);

    if (lm < 4)
        #pragma unroll
        for (int nt = 0; nt < 8; ++nt) {
            uint2 gw;
            gw.x = pk2(gacc[nt][0], gacc[nt][1]);
            gw.y = pk2(gacc[nt][2], gacc[nt][3]);
            *(uint2*)(Gb + (size_t)(nloc + lm) * 128 + nt * 16 + quad * 4) = gw;
        }
}

// ---------------------------------------------------------------------------
// phase 2 LDS (shorts):
//   [0,16384)      w2f  : W2 frags (4 ks), f=nt*4+ks
//   [16384,32768)  w1df : (W1 rows 0..127)-(rows 128..255) frags, f=nt*4+ks
//   [32768,33536)  W1r  : W1 rows 256..258 fp32 [3][128]
//   [33536,49920)  baseW: 16 waves x [4 nodes][128 c1] fp32
// total 49920 shorts = 99840 B
#define LDS2_BYTES 99840

__global__ __launch_bounds__(1024, 4) void edge_phase2(
    const float* __restrict__ h, const float* __restrict__ pos,
    const int* __restrict__ idx,
    const float* __restrict__ W1, const float* __restrict__ W2,
    const float* __restrict__ b1, const float* __restrict__ b2,
    const float* __restrict__ gamma, const float* __restrict__ beta,
    const short* __restrict__ G,
    float* __restrict__ out)
{
    extern __shared__ short lds[];
    float* ldsF = (float*)lds;
    const int tid = threadIdx.x, wave = tid >> 6, lane = tid & 63;
    const int quad = lane >> 4, lm = lane & 15;

    // ---- swizzle w2f + w1df ----
    for (int c = tid; c < 4096; c += 1024) {
        const int l = c & 63, fi = c >> 6;
        const int lrow = (l >> 4) * 8, lcol = l & 15;
        U8 t;
        if (fi < 32) {                        // w2f
            int ks = fi & 3, nt = fi >> 2;
            int row0 = ks * 32 + lrow, col = nt * 16 + lcol;
            #pragma unroll
            for (int p = 0; p < 4; ++p)
                t.u[p] = pk2(W2[(row0 + 2*p) * 128 + col],
                             W2[(row0 + 2*p + 1) * 128 + col]);
        } else {                              // w1df = W1a - W1b
            int f2 = fi - 32, ks = f2 & 3, nt = f2 >> 2;
            int row0 = ks * 32 + lrow, col = nt * 16 + lcol;
            #pragma unroll
            for (int p = 0; p < 4; ++p) {
                int r0 = row0 + 2 * p;
                float v0 = W1[r0 * 128 + col]       - W1[(r0 + 128) * 128 + col];
                float v1 = W1[(r0 + 1) * 128 + col] - W1[(r0 + 129) * 128 + col];
                t.u[p] = pk2(v0, v1);
            }
        }
        ((bf16x8*)lds)[c] = t.v;
    }
    if (tid < 384)                            // W1r rows 256..258, fp32
        ldsF[16384 + tid] = W1[(256 + (tid >> 7)) * 128 + (tid & 127)];

    float b2v[8];
    #pragma unroll
    for (int nt = 0; nt < 8; ++nt) b2v[nt] = b2[nt * 16 + lm];
    const float gv0 = gamma[(quad * 2) * 16 + lm];
    const float gv1 = gamma[(quad * 2 + 1) * 16 + lm];
    const float be0 = beta[(quad * 2) * 16 + lm];
    const float be1 = beta[(quad * 2 + 1) * 16 + lm];

    __syncthreads();

    const bf16x8* w2frag = (const bf16x8*)lds;           // f = nt*4+ks
    const bf16x8* w1df   = (const bf16x8*)lds + 2048;
    const float*  w1rL   = ldsF + 16384;                 // [3][128]
    float* baseW = ldsF + 16768 + wave * 512;            // [4 nodes][128 c1]

    const int sb = (blockIdx.x & 7) * 32 + (blockIdx.x >> 3);
    const int node0 = sb * 64 + wave * 4;
    const int bidx = node0 >> 11, nloc = node0 & 2047;
    const float4* hb4 = (const float4*)h + (size_t)bidx * NPTS * 32;
    const float*  pb  = pos + (size_t)bidx * NPTS * 3;
    const short*  Gb  = G + (size_t)bidx * NPTS * 128;

    int idxv[4];
    #pragma unroll
    for (int ni = 0; ni < 4; ++ni)
        idxv[ni] = idx[(node0 + ni) * KNBR + lm];

    // early G prefetch for node 0 (hidden under phase-B MFMAs)
    bf16x8 gcur[4], gnxt[4];
    #pragma unroll
    for (int ks = 0; ks < 4; ++ks)
        gcur[ks] = *(const bf16x8*)(Gb + (size_t)idxv[0] * 128 + ks * 32 + quad * 8);

    // ---- phase B (transposed, R12-proven): base = h_i.W1d + b1 -> LDS ----
    {
        const float4* hsrc = hb4 + (size_t)(nloc + (lm & 3)) * 32;
        bf16x8 af[4];
        #pragma unroll
        for (int ks = 0; ks < 4; ++ks) {
            float4 p0 = hsrc[ks * 8 + quad * 2];
            float4 p1 = hsrc[ks * 8 + quad * 2 + 1];
            U8 t;
            t.u[0] = pk2(p0.x, p0.y); t.u[1] = pk2(p0.z, p0.w);
            t.u[2] = pk2(p1.x, p1.y); t.u[3] = pk2(p1.z, p1.w);
            af[ks] = t.v;
        }
        f32x4 bacc[8];
        #pragma unroll
        for (int nt = 0; nt < 8; ++nt) {
            F4 bi; bi.q = *(const float4*)(b1 + nt * 16 + quad * 4);
            bacc[nt] = bi.v;
        }
        #pragma unroll
        for (int ks = 0; ks < 4; ++ks)
            #pragma unroll
            for (int nt = 0; nt < 8; ++nt)
                bacc[nt] = __builtin_amdgcn_mfma_f32_16x16x32_bf16(
                    w1df[(nt * 4 + ks) * 64 + lane], af[ks], bacc[nt], 0, 0, 0);
        if (lm < 4)
            #pragma unroll
            for (int nt = 0; nt < 8; ++nt) {
                F4 o; o.v = bacc[nt];
                *(float4*)(baseW + lm * 128 + nt * 16 + quad * 4) = o.q;
            }
        // same-wave DS write->read is in-order (R13-proven): no barrier needed.
    }

    // ---- per-node: gather G[j] -> hidden (A-frag layout) -> L2 -> epilogue --
    #pragma unroll
    for (int ni = 0; ni < 4; ++ni) {
        const int j = idxv[ni], i = nloc + ni;
        const float rx = pb[3*j]   - pb[3*i];
        const float ry = pb[3*j+1] - pb[3*i+1];
        const float rz = pb[3*j+2] - pb[3*i+2];

        bf16x8 a2[4];
        #pragma unroll
        for (int ks = 0; ks < 4; ++ks) {
            U8 g; g.v = gcur[ks];
            float gf[8];
            #pragma unroll
            for (int p = 0; p < 4; ++p) {
                gf[2*p]   = __builtin_bit_cast(float, g.u[p] << 16);
                gf[2*p+1] = __builtin_bit_cast(float, g.u[p] & 0xffff0000u);
            }
            const int ko = ks * 32 + quad * 8;
            F4 bl0, bl1, w00, w01, w10, w11, w20, w21;
            bl0.q = *(const float4*)(baseW + ni * 128 + ko);
            bl1.q = *(const float4*)(baseW + ni * 128 + ko + 4);
            w00.q = *(const float4*)(w1rL + ko);       w01.q = *(const float4*)(w1rL + ko + 4);
            w10.q = *(const float4*)(w1rL + 128 + ko); w11.q = *(const float4*)(w1rL + 128 + ko + 4);
            w20.q = *(const float4*)(w1rL + 256 + ko); w21.q = *(const float4*)(w1rL + 256 + ko + 4);
            float gl[8];
            #pragma unroll
            for (int e = 0; e < 8; ++e) {
                float bb = (e < 4) ? bl0.v[e] : bl1.v[e-4];
                float w0 = (e < 4) ? w00.v[e] : w01.v[e-4];
                float w1v= (e < 4) ? w10.v[e] : w11.v[e-4];
                float w2v= (e < 4) ? w20.v[e] : w21.v[e-4];
                float hp = gf[e] + bb;
                hp = fmaf(rx, w0, hp);
                hp = fmaf(ry, w1v, hp);
                hp = fmaf(rz, w2v, hp);
                gl[e] = gelu(hp);
            }
            U8 t;
            t.u[0] = pk2(gl[0], gl[1]); t.u[1] = pk2(gl[2], gl[3]);
            t.u[2] = pk2(gl[4], gl[5]); t.u[3] = pk2(gl[6], gl[7]);
            a2[ks] = t.v;
        }

        if (ni < 3) {
            #pragma unroll
            for (int ks = 0; ks < 4; ++ks)
                gnxt[ks] = *(const bf16x8*)(Gb + (size_t)idxv[ni+1] * 128 + ks * 32 + quad * 8);
        }

        float vA[8];
        #pragma unroll
        for (int nt = 0; nt < 8; ++nt) {
            f32x4 cA = (f32x4){0.f, 0.f, 0.f, 0.f};
            #pragma unroll
            for (int ks = 0; ks < 4; ++ks)
                cA = __builtin_amdgcn_mfma_f32_16x16x32_bf16(
                    a2[ks], w2frag[(nt * 4 + ks) * 64 + lane], cA, 0, 0, 0);
            float mx = fmaxf(fmaxf(cA[0], cA[1]), fmaxf(cA[2], cA[3]));
            float mn = fminf(fminf(cA[0], cA[1]), fminf(cA[2], cA[3]));
            mx = fmaxf(mx, __shfl_xor(mx, 16, 64));
            mx = fmaxf(mx, __shfl_xor(mx, 32, 64));
            mn = fminf(mn, __shfl_xor(mn, 16, 64));
            mn = fminf(mn, __shfl_xor(mn, 32, 64));
            vA[nt] = fmaxf(gelu(mx + b2v[nt]), gelu(mn + b2v[nt]));
        }

        float s = 0.f, s2 = 0.f;
        #pragma unroll
        for (int nt = 0; nt < 8; ++nt) { s += vA[nt]; s2 += vA[nt] * vA[nt]; }
        #pragma unroll
        for (int off = 1; off <= 8; off <<= 1) {
            s  += __shfl_xor(s,  off, 64);
            s2 += __shfl_xor(s2, off, 64);
        }
        const float mu  = s * (1.0f / 128.0f);
        const float var = s2 * (1.0f / 128.0f) - mu * mu;
        const float inv = rsqrtf(var + 1e-5f);
        float* orow = out + (size_t)(node0 + ni) * 128;
        orow[(quad * 2) * 16 + lm]     = (vA[quad * 2]     - mu) * inv * gv0 + be0;
        orow[(quad * 2 + 1) * 16 + lm] = (vA[quad * 2 + 1] - mu) * inv * gv1 + be1;

        #pragma unroll
        for (int ks = 0; ks < 4; ++ks) gcur[ks] = gnxt[ks];
    }
}

extern "C" void kernel_launch(void* const* d_in, const int* in_sizes, int n_in,
                              void* d_out, int out_size, void* d_ws, size_t ws_size,
                              hipStream_t stream) {
    const float* h     = (const float*)d_in[0];
    const float* pos   = (const float*)d_in[1];
    const int*   idx   = (const int*)  d_in[2];
    const float* W1    = (const float*)d_in[3];
    const float* b1    = (const float*)d_in[4];
    const float* W2    = (const float*)d_in[5];
    const float* b2    = (const float*)d_in[6];
    const float* gamma = (const float*)d_in[7];
    const float* beta  = (const float*)d_in[8];
    float* out = (float*)d_out;

    short* G = (short*)d_ws;                     // 16384*128 bf16 = 4 MB

    edge_phase1<<<256, 1024, 0, stream>>>(h, W1, G);

    hipFuncSetAttribute((const void*)edge_phase2,
                        hipFuncAttributeMaxDynamicSharedMemorySize, LDS2_BYTES);
    edge_phase2<<<256, 1024, LDS2_BYTES, stream>>>(
        h, pos, idx, W1, W2, b1, b2, gamma, beta, G, out);
}

// Round 16
// 121.444 us; speedup vs baseline: 1.4387x; 1.4387x over previous
//
#include <hip/hip_runtime.h>

#define NPTS 2048
#define KNBR 16

typedef __attribute__((ext_vector_type(8))) short bf16x8;
typedef __attribute__((ext_vector_type(4))) float f32x4;
union U8 { bf16x8 v; unsigned u[4]; };
union F4 { f32x4 v; float4 q; };

// gfx950 packed f32->bf16 (RNE)
static __device__ __forceinline__ unsigned pk2(float lo, float hi) {
    unsigned r;
    asm("v_cvt_pk_bf16_f32 %0, %1, %2" : "=v"(r) : "v"(lo), "v"(hi));
    return r;
}

// tanh-approx gelu, sigmoid form via exp2 (R11-R13-proven)
static __device__ __forceinline__ float gelu(float x) {
    float x2 = x * x;
    float u  = x * fmaf(x2, 0.044715f, 1.0f);
    float e  = __builtin_amdgcn_exp2f(u * -2.3022083f);
    return x * __builtin_amdgcn_rcpf(1.0f + e);
}

static __device__ __forceinline__ float bfhi(unsigned u) {
    return __builtin_bit_cast(float, u << 16);
}
static __device__ __forceinline__ float bflo(unsigned u) {
    return __builtin_bit_cast(float, u & 0xffff0000u);
}

// ---------------------------------------------------------------------------
// phase 1: G[node][c1] = (h[node] . W1 rows 128..255)[c1], bf16, to d_ws.
// Transposed MFMA (R12-proven): lane(q,lm) reg r = G[c1=16nt+4q+r][node lm&3].
__global__ __launch_bounds__(1024) void edge_phase1(
    const float* __restrict__ h, const float* __restrict__ W1,
    short* __restrict__ G)
{
    __shared__ short w1bfs[16384];
    const int tid = threadIdx.x, lane = tid & 63, wave = tid >> 6;
    const int quad = lane >> 4, lm = lane & 15;

    for (int c = tid; c < 2048; c += 1024) {
        const int l = c & 63, fi = c >> 6;
        const int lrow = (l >> 4) * 8, lcol = l & 15;
        const int ks = fi & 3, nt = fi >> 2;
        const int row0 = 128 + ks * 32 + lrow, col = nt * 16 + lcol;
        U8 t;
        #pragma unroll
        for (int p = 0; p < 4; ++p)
            t.u[p] = pk2(W1[(row0 + 2*p) * 128 + col],
                         W1[(row0 + 2*p + 1) * 128 + col]);
        ((bf16x8*)w1bfs)[c] = t.v;
    }
    __syncthreads();
    const bf16x8* w1bf = (const bf16x8*)w1bfs;

    const int sb = (blockIdx.x & 7) * 32 + (blockIdx.x >> 3);
    const int node0 = sb * 64 + wave * 4;
    const int bidx = node0 >> 11, nloc = node0 & 2047;
    const float4* hb4 = (const float4*)h + (size_t)bidx * NPTS * 32;
    short* Gb = G + (size_t)bidx * NPTS * 128;

    const float4* hsrc = hb4 + (size_t)(nloc + (lm & 3)) * 32;
    bf16x8 af[4];
    #pragma unroll
    for (int ks = 0; ks < 4; ++ks) {
        float4 p0 = hsrc[ks * 8 + quad * 2];
        float4 p1 = hsrc[ks * 8 + quad * 2 + 1];
        U8 t;
        t.u[0] = pk2(p0.x, p0.y); t.u[1] = pk2(p0.z, p0.w);
        t.u[2] = pk2(p1.x, p1.y); t.u[3] = pk2(p1.z, p1.w);
        af[ks] = t.v;
    }
    f32x4 gacc[8];
    #pragma unroll
    for (int nt = 0; nt < 8; ++nt) gacc[nt] = (f32x4){0.f, 0.f, 0.f, 0.f};
    #pragma unroll
    for (int ks = 0; ks < 4; ++ks)
        #pragma unroll
        for (int nt = 0; nt < 8; ++nt)
            gacc[nt] = __builtin_amdgcn_mfma_f32_16x16x32_bf16(
                w1bf[(nt * 4 + ks) * 64 + lane], af[ks], gacc[nt], 0, 0, 0);

    if (lm < 4)
        #pragma unroll
        for (int nt = 0; nt < 8; ++nt) {
            uint2 gw;
            gw.x = pk2(gacc[nt][0], gacc[nt][1]);
            gw.y = pk2(gacc[nt][2], gacc[nt][3]);
            *(uint2*)(Gb + (size_t)(nloc + lm) * 128 + nt * 16 + quad * 4) = gw;
        }
}

// ---------------------------------------------------------------------------
// phase 2 LDS (shorts):
//   [0,16384)      w2f  : W2 frags (4 ks), f=nt*4+ks
//   [16384,32768)  w1df : (W1 rows 0..127)-(rows 128..255) frags, f=nt*4+ks
//   [32768,33536)  W1r  : W1 rows 256..258 fp32 [3][128]
//   [33536,49920)  baseW: 16 waves x [4 nodes][128 c1] fp32
// total 49920 shorts = 99840 B
#define LDS2_BYTES 99840

__global__ __launch_bounds__(1024, 4) void edge_phase2(
    const float* __restrict__ h, const float* __restrict__ pos,
    const int* __restrict__ idx,
    const float* __restrict__ W1, const float* __restrict__ W2,
    const float* __restrict__ b1, const float* __restrict__ b2,
    const float* __restrict__ gamma, const float* __restrict__ beta,
    const short* __restrict__ G,
    float* __restrict__ out)
{
    extern __shared__ short lds[];
    float* ldsF = (float*)lds;
    const int tid = threadIdx.x, wave = tid >> 6, lane = tid & 63;
    const int quad = lane >> 4, lm = lane & 15;

    // ---- swizzle w2f + w1df ----
    for (int c = tid; c < 4096; c += 1024) {
        const int l = c & 63, fi = c >> 6;
        const int lrow = (l >> 4) * 8, lcol = l & 15;
        U8 t;
        if (fi < 32) {                        // w2f
            int ks = fi & 3, nt = fi >> 2;
            int row0 = ks * 32 + lrow, col = nt * 16 + lcol;
            #pragma unroll
            for (int p = 0; p < 4; ++p)
                t.u[p] = pk2(W2[(row0 + 2*p) * 128 + col],
                             W2[(row0 + 2*p + 1) * 128 + col]);
        } else {                              // w1df = W1a - W1b
            int f2 = fi - 32, ks = f2 & 3, nt = f2 >> 2;
            int row0 = ks * 32 + lrow, col = nt * 16 + lcol;
            #pragma unroll
            for (int p = 0; p < 4; ++p) {
                int r0 = row0 + 2 * p;
                float v0 = W1[r0 * 128 + col]       - W1[(r0 + 128) * 128 + col];
                float v1 = W1[(r0 + 1) * 128 + col] - W1[(r0 + 129) * 128 + col];
                t.u[p] = pk2(v0, v1);
            }
        }
        ((bf16x8*)lds)[c] = t.v;
    }
    if (tid < 384)                            // W1r rows 256..258, fp32
        ldsF[16384 + tid] = W1[(256 + (tid >> 7)) * 128 + (tid & 127)];

    float b2v[8];
    #pragma unroll
    for (int nt = 0; nt < 8; ++nt) b2v[nt] = b2[nt * 16 + lm];
    const float gv0 = gamma[(quad * 2) * 16 + lm];
    const float gv1 = gamma[(quad * 2 + 1) * 16 + lm];
    const float be0 = beta[(quad * 2) * 16 + lm];
    const float be1 = beta[(quad * 2 + 1) * 16 + lm];

    __syncthreads();

    const bf16x8* w2frag = (const bf16x8*)lds;           // f = nt*4+ks
    const bf16x8* w1df   = (const bf16x8*)lds + 2048;
    const float*  w1rL   = ldsF + 16384;                 // [3][128]
    float* baseW = ldsF + 16768 + wave * 512;            // [4 nodes][128 c1]

    const int sb = (blockIdx.x & 7) * 32 + (blockIdx.x >> 3);
    const int node0 = sb * 64 + wave * 4;
    const int bidx = node0 >> 11, nloc = node0 & 2047;
    const float4* hb4 = (const float4*)h + (size_t)bidx * NPTS * 32;
    const float*  pb  = pos + (size_t)bidx * NPTS * 3;
    const short*  Gb  = G + (size_t)bidx * NPTS * 128;

    int idxv[4];
    #pragma unroll
    for (int ni = 0; ni < 4; ++ni)
        idxv[ni] = idx[(node0 + ni) * KNBR + lm];

    // early G prefetch for node 0 (hidden under phase-B MFMAs)
    bf16x8 gcur[4], gnxt[4];
    #pragma unroll
    for (int ks = 0; ks < 4; ++ks)
        gcur[ks] = *(const bf16x8*)(Gb + (size_t)idxv[0] * 128 + ks * 32 + quad * 8);

    // ---- phase B (transposed, R12-proven): base = h_i.W1d + b1 -> LDS ----
    {
        const float4* hsrc = hb4 + (size_t)(nloc + (lm & 3)) * 32;
        bf16x8 af[4];
        #pragma unroll
        for (int ks = 0; ks < 4; ++ks) {
            float4 p0 = hsrc[ks * 8 + quad * 2];
            float4 p1 = hsrc[ks * 8 + quad * 2 + 1];
            U8 t;
            t.u[0] = pk2(p0.x, p0.y); t.u[1] = pk2(p0.z, p0.w);
            t.u[2] = pk2(p1.x, p1.y); t.u[3] = pk2(p1.z, p1.w);
            af[ks] = t.v;
        }
        f32x4 bacc[8];
        #pragma unroll
        for (int nt = 0; nt < 8; ++nt) {
            F4 bi; bi.q = *(const float4*)(b1 + nt * 16 + quad * 4);
            bacc[nt] = bi.v;
        }
        #pragma unroll
        for (int ks = 0; ks < 4; ++ks)
            #pragma unroll
            for (int nt = 0; nt < 8; ++nt)
                bacc[nt] = __builtin_amdgcn_mfma_f32_16x16x32_bf16(
                    w1df[(nt * 4 + ks) * 64 + lane], af[ks], bacc[nt], 0, 0, 0);
        if (lm < 4)
            #pragma unroll
            for (int nt = 0; nt < 8; ++nt) {
                F4 o; o.v = bacc[nt];
                *(float4*)(baseW + lm * 128 + nt * 16 + quad * 4) = o.q;
            }
        // same-wave DS write->read is in-order (R13-proven): no barrier needed.
    }

    // ---- per-node: gather G[j] -> hidden (A-frag layout) -> L2 -> epilogue --
    #pragma unroll
    for (int ni = 0; ni < 4; ++ni) {
        const int j = idxv[ni], i = nloc + ni;
        const float rx = pb[3*j]   - pb[3*i];
        const float ry = pb[3*j+1] - pb[3*i+1];
        const float rz = pb[3*j+2] - pb[3*i+2];

        // hidden build: ALL explicit scalars (no private arrays -> no scratch)
        bf16x8 a2[4];
        #pragma unroll
        for (int ks = 0; ks < 4; ++ks) {
            U8 g; g.v = gcur[ks];
            const float g0 = bfhi(g.u[0]), g1 = bflo(g.u[0]);
            const float g2 = bfhi(g.u[1]), g3 = bflo(g.u[1]);
            const float g4 = bfhi(g.u[2]), g5 = bflo(g.u[2]);
            const float g6 = bfhi(g.u[3]), g7 = bflo(g.u[3]);
            const int ko = ks * 32 + quad * 8;
            const float4 ba0 = *(const float4*)(baseW + ni * 128 + ko);
            const float4 ba1 = *(const float4*)(baseW + ni * 128 + ko + 4);
            const float4 wx0 = *(const float4*)(w1rL + ko);
            const float4 wx1 = *(const float4*)(w1rL + ko + 4);
            const float4 wy0 = *(const float4*)(w1rL + 128 + ko);
            const float4 wy1 = *(const float4*)(w1rL + 128 + ko + 4);
            const float4 wz0 = *(const float4*)(w1rL + 256 + ko);
            const float4 wz1 = *(const float4*)(w1rL + 256 + ko + 4);
            const float h0 = gelu(fmaf(rz, wz0.x, fmaf(ry, wy0.x, fmaf(rx, wx0.x, g0 + ba0.x))));
            const float h1 = gelu(fmaf(rz, wz0.y, fmaf(ry, wy0.y, fmaf(rx, wx0.y, g1 + ba0.y))));
            const float h2 = gelu(fmaf(rz, wz0.z, fmaf(ry, wy0.z, fmaf(rx, wx0.z, g2 + ba0.z))));
            const float h3 = gelu(fmaf(rz, wz0.w, fmaf(ry, wy0.w, fmaf(rx, wx0.w, g3 + ba0.w))));
            const float h4 = gelu(fmaf(rz, wz1.x, fmaf(ry, wy1.x, fmaf(rx, wx1.x, g4 + ba1.x))));
            const float h5 = gelu(fmaf(rz, wz1.y, fmaf(ry, wy1.y, fmaf(rx, wx1.y, g5 + ba1.y))));
            const float h6 = gelu(fmaf(rz, wz1.z, fmaf(ry, wy1.z, fmaf(rx, wx1.z, g6 + ba1.z))));
            const float h7 = gelu(fmaf(rz, wz1.w, fmaf(ry, wy1.w, fmaf(rx, wx1.w, g7 + ba1.w))));
            U8 t;
            t.u[0] = pk2(h0, h1); t.u[1] = pk2(h2, h3);
            t.u[2] = pk2(h4, h5); t.u[3] = pk2(h6, h7);
            a2[ks] = t.v;
        }

        if (ni < 3) {
            #pragma unroll
            for (int ks = 0; ks < 4; ++ks)
                gnxt[ks] = *(const bf16x8*)(Gb + (size_t)idxv[ni+1] * 128 + ks * 32 + quad * 8);
        }

        // layer 2 + epilogue; no vA[] array — running sums + cndmask selects
        float s = 0.f, s2 = 0.f, sel0 = 0.f, sel1 = 0.f;
        #pragma unroll
        for (int nt = 0; nt < 8; ++nt) {
            f32x4 cA = (f32x4){0.f, 0.f, 0.f, 0.f};
            #pragma unroll
            for (int ks = 0; ks < 4; ++ks)
                cA = __builtin_amdgcn_mfma_f32_16x16x32_bf16(
                    a2[ks], w2frag[(nt * 4 + ks) * 64 + lane], cA, 0, 0, 0);
            float mx = fmaxf(fmaxf(cA[0], cA[1]), fmaxf(cA[2], cA[3]));
            float mn = fminf(fminf(cA[0], cA[1]), fminf(cA[2], cA[3]));
            mx = fmaxf(mx, __shfl_xor(mx, 16, 64));
            mx = fmaxf(mx, __shfl_xor(mx, 32, 64));
            mn = fminf(mn, __shfl_xor(mn, 16, 64));
            mn = fminf(mn, __shfl_xor(mn, 32, 64));
            float v = fmaxf(gelu(mx + b2v[nt]), gelu(mn + b2v[nt]));
            s += v; s2 += v * v;
            sel0 = (nt == quad * 2)     ? v : sel0;
            sel1 = (nt == quad * 2 + 1) ? v : sel1;
        }
        #pragma unroll
        for (int off = 1; off <= 8; off <<= 1) {
            s  += __shfl_xor(s,  off, 64);
            s2 += __shfl_xor(s2, off, 64);
        }
        const float mu  = s * (1.0f / 128.0f);
        const float var = s2 * (1.0f / 128.0f) - mu * mu;
        const float inv = rsqrtf(var + 1e-5f);
        float* orow = out + (size_t)(node0 + ni) * 128;
        orow[(quad * 2) * 16 + lm]     = (sel0 - mu) * inv * gv0 + be0;
        orow[(quad * 2 + 1) * 16 + lm] = (sel1 - mu) * inv * gv1 + be1;

        #pragma unroll
        for (int ks = 0; ks < 4; ++ks) gcur[ks] = gnxt[ks];
    }
}

extern "C" void kernel_launch(void* const* d_in, const int* in_sizes, int n_in,
                              void* d_out, int out_size, void* d_ws, size_t ws_size,
                              hipStream_t stream) {
    const float* h     = (const float*)d_in[0];
    const float* pos   = (const float*)d_in[1];
    const int*   idx   = (const int*)  d_in[2];
    const float* W1    = (const float*)d_in[3];
    const float* b1    = (const float*)d_in[4];
    const float* W2    = (const float*)d_in[5];
    const float* b2    = (const float*)d_in[6];
    const float* gamma = (const float*)d_in[7];
    const float* beta  = (const float*)d_in[8];
    float* out = (float*)d_out;

    short* G = (short*)d_ws;                     // 16384*128 bf16 = 4 MB

    edge_phase1<<<256, 1024, 0, stream>>>(h, W1, G);

    hipFuncSetAttribute((const void*)edge_phase2,
                        hipFuncAttributeMaxDynamicSharedMemorySize, LDS2_BYTES);
    edge_phase2<<<256, 1024, LDS2_BYTES, stream>>>(
        h, pos, idx, W1, W2, b1, b2, gamma, beta, G, out);
}